// Round 7
// baseline (288.312 us; speedup 1.0000x reference)
//
#include <hip/hip_runtime.h>

#define Bn 4096
#define En 1024
#define On 16
#define Hn 1024
#define MT 80   // max padded 64-row m-tiles (4096/64 + 16 = 80)

using floatx4 = __attribute__((ext_vector_type(4))) float;
using float4v = __attribute__((ext_vector_type(4))) float;
using bf16x8  = __attribute__((ext_vector_type(8))) __bf16;
using short8v = __attribute__((ext_vector_type(8))) short;

__device__ inline unsigned short f2bf(float f) {
    unsigned u = __builtin_bit_cast(unsigned, f);
    u += 0x7fffu + ((u >> 16) & 1u);   // RNE (inputs finite)
    return (unsigned short)(u >> 16);
}

// async global->LDS: gp is PER-LANE global addr, LDS dest = wave-uniform base + lane*16B
#define GLOAD16(gp, lp) __builtin_amdgcn_global_load_lds( \
    (const __attribute__((address_space(1))) unsigned int*)(gp), \
    (__attribute__((address_space(3))) unsigned int*)(lp), 16, 0, 0)

// ---- bucket (round-5-proven logic, 256 thr) + tile2o map ----
// meta[0..16]=padded offsets, meta[20+o]=cnt, meta[40+t]=tile2o (or -1)
__global__ __launch_bounds__(256) void bucket_kernel(const int* __restrict__ op_idx,
                                                     int* __restrict__ sidx_pad,
                                                     int* __restrict__ meta) {
    __shared__ int cnt[On], cur[On], po[On + 1];
    int tid = threadIdx.x;
    if (tid < On) { cnt[tid] = 0; cur[tid] = 0; }
    __syncthreads();
    for (int i = tid; i < Bn; i += 256) atomicAdd(&cnt[op_idx[i]], 1);
    __syncthreads();
    if (tid == 0) {
        int ps = 0;
        for (int o = 0; o < On; ++o) { po[o] = ps; ps += (cnt[o] + 63) & ~63; }
        po[On] = ps;
    }
    __syncthreads();
    for (int p = tid; p < MT * 64; p += 256) sidx_pad[p] = -1;
    __syncthreads();
    for (int i = tid; i < Bn; i += 256) {
        int o = op_idx[i];
        sidx_pad[po[o] + atomicAdd(&cur[o], 1)] = i;
    }
    if (tid <= On) meta[tid] = po[tid];
    if (tid < On)  meta[20 + tid] = cnt[tid];
    if (tid < MT) {
        int o2 = -1;
        for (int o = 0; o < On; ++o)
            if (tid * 64 >= po[o] && tid * 64 < po[o + 1]) o2 = o;
        meta[40 + tid] = o2;
    }
}

// ---- W[e][o][h] fp32 -> Wt tiled [o][nb 16][gg 128][row 64][8] bf16 ----
__global__ __launch_bounds__(256) void wtrans_kernel(const float* __restrict__ W,
                                                     unsigned short* __restrict__ Wt) {
    __shared__ float tile[64][65];
    int o = blockIdx.z, e0 = blockIdx.y * 64, h0 = blockIdx.x * 64;
    int t = threadIdx.x;
    int er = t >> 4, c4 = (t & 15) * 4;
#pragma unroll
    for (int r = 0; r < 4; ++r) {
        const float* p = W + ((size_t)(e0 + er + 16 * r) * On + o) * Hn + h0 + c4;
        *(float4v*)&tile[er + 16 * r][c4] = *(const float4v*)p;
    }
    __syncthreads();
    int row = t & 63, gl = t >> 6;
#pragma unroll
    for (int r = 0; r < 2; ++r) {
        int ggl = gl + 4 * r;
        short8v v;
#pragma unroll
        for (int j = 0; j < 8; ++j) v[j] = (short)f2bf(tile[ggl * 8 + j][row]);
        size_t dst = (((size_t)o * 16 + (h0 >> 6)) * 128 + (e0 >> 3) + ggl) * 512 + row * 8;
        *(short8v*)(Wt + dst) = v;   // 64 lanes -> 1KB contiguous
    }
}

// ---- gather + cvt x -> xs tiled [tile][gg 128][row 64][8] bf16 ----
__global__ __launch_bounds__(256) void xprep_kernel(const float* __restrict__ x,
                                                    const int* __restrict__ sidx_pad,
                                                    const int* __restrict__ meta,
                                                    unsigned short* __restrict__ xs) {
    int p0 = blockIdx.x * 64;
    if (p0 >= meta[On]) return;
    int t = threadIdx.x, row = t & 63, gl = t >> 6;
    int src = sidx_pad[p0 + row];
    const float* xr = (src >= 0) ? (x + (size_t)src * En) : nullptr;
    unsigned short* xbase = xs + (size_t)(p0 >> 6) * 65536 + row * 8;
#pragma unroll 4
    for (int r = 0; r < 32; ++r) {
        int gg = gl + r * 4;
        short8v v = {};
        if (xr) {
            float4v f0 = *(const float4v*)(xr + gg * 8);
            float4v f1 = *(const float4v*)(xr + gg * 8 + 4);
#pragma unroll
            for (int j = 0; j < 4; ++j) { v[j] = (short)f2bf(f0[j]); v[4 + j] = (short)f2bf(f1[j]); }
        }
        *(short8v*)(xbase + (size_t)gg * 512) = v;
    }
}

// ---- layer 1: h1T = relu(xs @ Wt1^T + b1), single-barrier pipelined ----
__global__ __launch_bounds__(256, 4) void gemm1_kernel(
    const unsigned short* __restrict__ xs, const unsigned short* __restrict__ Wt,
    const float* __restrict__ bias1, const int* __restrict__ meta,
    unsigned short* __restrict__ h1T) {
    int t = blockIdx.y;
    int o = meta[40 + t];
    if (o < 0) return;
    int nb = blockIdx.x;

    __shared__ unsigned short As[2][8][64][8];   // 2 x 8 KB
    __shared__ unsigned short Bs[2][8][64][8];   // 2 x 8 KB

    int tid = threadIdx.x, lane = tid & 63, wave = tid >> 6;
    // per-lane global bases: lane covers row `lane` of each 64x8 granule
    const unsigned short* Ab = xs + (size_t)t * 65536 + lane * 8;
    const unsigned short* Bb = Wt + ((size_t)o * 16 + nb) * 65536 + lane * 8;

    floatx4 acc[2][2] = {};
    int wm = (wave & 1) * 32, wn = (wave >> 1) * 32;
    int l15 = lane & 15, kg = lane >> 4;
    int g0 = wave * 2, g1 = wave * 2 + 1;

    GLOAD16(Ab + g0 * 512, &As[0][g0][0][0]);
    GLOAD16(Ab + g1 * 512, &As[0][g1][0][0]);
    GLOAD16(Bb + g0 * 512, &Bs[0][g0][0][0]);
    GLOAD16(Bb + g1 * 512, &Bs[0][g1][0][0]);
    __syncthreads();

    for (int it = 0; it < 16; ++it) {
        int p = it & 1;
        if (it < 15) {   // issue next tile first: full region covers latency
            int off = (it + 1) * 4096;
            GLOAD16(Ab + off + g0 * 512, &As[p ^ 1][g0][0][0]);
            GLOAD16(Ab + off + g1 * 512, &As[p ^ 1][g1][0][0]);
            GLOAD16(Bb + off + g0 * 512, &Bs[p ^ 1][g0][0][0]);
            GLOAD16(Bb + off + g1 * 512, &Bs[p ^ 1][g1][0][0]);
        }
#pragma unroll
        for (int ks = 0; ks < 2; ++ks) {
            int g = ks * 4 + kg;
            bf16x8 a0 = *(const bf16x8*)&As[p][g][wm + l15][0];
            bf16x8 a1 = *(const bf16x8*)&As[p][g][wm + 16 + l15][0];
            bf16x8 b0 = *(const bf16x8*)&Bs[p][g][wn + l15][0];
            bf16x8 b1 = *(const bf16x8*)&Bs[p][g][wn + 16 + l15][0];
            acc[0][0] = __builtin_amdgcn_mfma_f32_16x16x32_bf16(a0, b0, acc[0][0], 0, 0, 0);
            acc[0][1] = __builtin_amdgcn_mfma_f32_16x16x32_bf16(a0, b1, acc[0][1], 0, 0, 0);
            acc[1][0] = __builtin_amdgcn_mfma_f32_16x16x32_bf16(a1, b0, acc[1][0], 0, 0, 0);
            acc[1][1] = __builtin_amdgcn_mfma_f32_16x16x32_bf16(a1, b1, acc[1][1], 0, 0, 0);
        }
        __syncthreads();
    }

    // epilogue: bias+relu, transpose to A-granule layout via LDS, contiguous dump
    unsigned short* ep = &As[0][0][0][0];   // [8 ggl][64 row][8]
    int n0 = nb * 64;
#pragma unroll
    for (int nt = 0; nt < 2; ++nt) {
        int col = wn + nt * 16 + l15;
        float bv = bias1[o * Hn + n0 + col];
#pragma unroll
        for (int mt = 0; mt < 2; ++mt)
#pragma unroll
            for (int r = 0; r < 4; ++r) {
                int row = wm + mt * 16 + kg * 4 + r;
                float v = acc[mt][nt][r] + bv;
                ep[((col >> 3) * 64 + row) * 8 + (col & 7)] = f2bf(v > 0.f ? v : 0.f);
            }
    }
    __syncthreads();
    unsigned short* dst = h1T + (size_t)t * 65536 + nb * 4096;
#pragma unroll
    for (int rr = 0; rr < 2; ++rr) {
        int idx = rr * 256 + tid;
        *(short8v*)(dst + idx * 8) = *(const short8v*)(ep + idx * 8);
    }
}

// ---- layer 2: out[orig] = relu(h1T @ Wt2^T + b2), scatter epilogue ----
__global__ __launch_bounds__(256, 4) void gemm2_kernel(
    const unsigned short* __restrict__ h1T, const unsigned short* __restrict__ Wt,
    const float* __restrict__ bias2, const int* __restrict__ sidx_pad,
    const int* __restrict__ meta, float* __restrict__ out) {
    int t = blockIdx.y;
    int o = meta[40 + t];
    if (o < 0) return;
    int nb = blockIdx.x;

    __shared__ unsigned short As[2][8][64][8];
    __shared__ unsigned short Bs[2][8][64][8];

    int tid = threadIdx.x, lane = tid & 63, wave = tid >> 6;
    const unsigned short* Ab = h1T + (size_t)t * 65536 + lane * 8;
    const unsigned short* Bb = Wt + ((size_t)o * 16 + nb) * 65536 + lane * 8;

    floatx4 acc[2][2] = {};
    int wm = (wave & 1) * 32, wn = (wave >> 1) * 32;
    int l15 = lane & 15, kg = lane >> 4;
    int g0 = wave * 2, g1 = wave * 2 + 1;

    GLOAD16(Ab + g0 * 512, &As[0][g0][0][0]);
    GLOAD16(Ab + g1 * 512, &As[0][g1][0][0]);
    GLOAD16(Bb + g0 * 512, &Bs[0][g0][0][0]);
    GLOAD16(Bb + g1 * 512, &Bs[0][g1][0][0]);
    __syncthreads();

    for (int it = 0; it < 16; ++it) {
        int p = it & 1;
        if (it < 15) {
            int off = (it + 1) * 4096;
            GLOAD16(Ab + off + g0 * 512, &As[p ^ 1][g0][0][0]);
            GLOAD16(Ab + off + g1 * 512, &As[p ^ 1][g1][0][0]);
            GLOAD16(Bb + off + g0 * 512, &Bs[p ^ 1][g0][0][0]);
            GLOAD16(Bb + off + g1 * 512, &Bs[p ^ 1][g1][0][0]);
        }
#pragma unroll
        for (int ks = 0; ks < 2; ++ks) {
            int g = ks * 4 + kg;
            bf16x8 a0 = *(const bf16x8*)&As[p][g][wm + l15][0];
            bf16x8 a1 = *(const bf16x8*)&As[p][g][wm + 16 + l15][0];
            bf16x8 b0 = *(const bf16x8*)&Bs[p][g][wn + l15][0];
            bf16x8 b1 = *(const bf16x8*)&Bs[p][g][wn + 16 + l15][0];
            acc[0][0] = __builtin_amdgcn_mfma_f32_16x16x32_bf16(a0, b0, acc[0][0], 0, 0, 0);
            acc[0][1] = __builtin_amdgcn_mfma_f32_16x16x32_bf16(a0, b1, acc[0][1], 0, 0, 0);
            acc[1][0] = __builtin_amdgcn_mfma_f32_16x16x32_bf16(a1, b0, acc[1][0], 0, 0, 0);
            acc[1][1] = __builtin_amdgcn_mfma_f32_16x16x32_bf16(a1, b1, acc[1][1], 0, 0, 0);
        }
        __syncthreads();
    }

    int n0 = nb * 64;
    float bv0 = bias2[o * Hn + n0 + wn + l15];
    float bv1 = bias2[o * Hn + n0 + wn + 16 + l15];
#pragma unroll
    for (int mt = 0; mt < 2; ++mt)
#pragma unroll
        for (int r = 0; r < 4; ++r) {
            int row = wm + mt * 16 + kg * 4 + r;
            int b = sidx_pad[t * 64 + row];
            if (b >= 0) {
                float* orow = out + (size_t)b * Hn + n0 + wn + l15;
                float v0 = acc[mt][0][r] + bv0;
                float v1 = acc[mt][1][r] + bv1;
                orow[0]  = v0 > 0.f ? v0 : 0.f;
                orow[16] = v1 > 0.f ? v1 : 0.f;
            }
        }
}

extern "C" void kernel_launch(void* const* d_in, const int* in_sizes, int n_in,
                              void* d_out, int out_size, void* d_ws, size_t ws_size,
                              hipStream_t stream) {
    const float* x      = (const float*)d_in[0];
    const int*   op_idx = (const int*)d_in[1];
    const float* W1     = (const float*)d_in[2];
    const float* bias1  = (const float*)d_in[3];
    const float* W2     = (const float*)d_in[4];
    const float* bias2  = (const float*)d_in[5];
    float* out = (float*)d_out;

    char* ws = (char*)d_ws;
    int* meta      = (int*)ws;                                       // 128 ints
    int* sidx_pad  = (int*)(ws + 1024);                              // 20 KB
    unsigned short* xs  = (unsigned short*)(ws + 65536);             // 10 MB tiled
    unsigned short* h1T = (unsigned short*)(ws + 65536 + 10485760);  // 10 MB tiled
    unsigned short* Wt  = (unsigned short*)(ws + 65536 + 20971520);  // 32 MB tiled

    hipLaunchKernelGGL(bucket_kernel, dim3(1), dim3(256), 0, stream,
                       op_idx, sidx_pad, meta);
    hipLaunchKernelGGL(wtrans_kernel, dim3(16, 16, On), dim3(256), 0, stream, W1, Wt);
    hipLaunchKernelGGL(xprep_kernel, dim3(MT), dim3(256), 0, stream,
                       x, sidx_pad, meta, xs);
    dim3 grid(16, MT);
    hipLaunchKernelGGL(gemm1_kernel, grid, dim3(256), 0, stream,
                       xs, Wt, bias1, meta, h1T);
    hipLaunchKernelGGL(wtrans_kernel, dim3(16, 16, On), dim3(256), 0, stream, W2, Wt);
    hipLaunchKernelGGL(gemm2_kernel, grid, dim3(256), 0, stream,
                       h1T, Wt, bias2, sidx_pad, meta, out);
}